// Round 4
// baseline (188.131 us; speedup 1.0000x reference)
//
#include <hip/hip_runtime.h>

// Fused morphological opening (22x22 flat SE), 8x3x1024x1024 f32, one kernel.
// opening = dilate(erode(x)); both separable. Per 64x64 output tile:
//   P0: colmin streamed global->regs->LDS (vertical van Herk in registers,
//       writes 85 rows x 108 cols of column-min into B; no input staging)
//   P1: rowmin over B rows -> eroded 85x85 (+ -inf border override), in-place
//   P2: rowmax over eroded rows -> 85x64, in-place
//   P3: colmax over B cols -> 64x64, direct coalesced global store
// B stride 116 (29 f4-groups, 29 odd): f4 base bank-group = 29*o mod 32 hits
// all 32 banks across lanes (SB=112 had gcd(28,32)=4 -> 4-way conflicts);
// col-direction scalar ops (lanes vary col) are <=2-way aliased (free).
// Window for index i: [i-11, i+10]. Erosion pads +inf outside image; eroded
// values outside the image are -inf for the dilation (border override in P1).

#define HH 1024
#define WW 1024
#define KW 22
#define SB 116
#define PINF __builtin_inff()

template<bool IS_MIN>
__device__ __forceinline__ float vop(float a, float b) {
    return IS_MIN ? fminf(a, b) : fmaxf(a, b);
}

// van Herk / Gil-Werman 1D sliding window (window KW=22), cout<=CMAX outputs.
// get(p): input at window-space p (output k's window = get(k..k+21)).
template<bool IS_MIN, int CMAX, class Get, class Put>
__device__ __forceinline__ void vanherk(int cout, Get get, Put put) {
    const float ID = IS_MIN ? PINF : -PINF;
    constexpr int NB = (CMAX + 2 * KW - 2) / KW;
    float Sprev[KW];
    #pragma unroll
    for (int j = 0; j < NB; ++j) {
        const int base = KW * j;
        int needed = cout + KW - 1 - base;
        if (needed > KW) needed = KW;
        float v[KW];
        #pragma unroll
        for (int m = 0; m < KW; ++m)
            v[m] = (m < needed) ? get(base + m) : ID;
        float p = ID;
        #pragma unroll
        for (int m = 0; m < KW; ++m) {
            p = vop<IS_MIN>(p, v[m]);
            const int k = base - (KW - 1) + m;
            if (k >= 0) {
                if (m == KW - 1) {
                    if (k < cout) put(k, p);
                } else {
                    if (k < cout) put(k, vop<IS_MIN>(Sprev[m + 1], p));
                }
            }
        }
        if (j < NB - 1) {
            float s = ID;
            #pragma unroll
            for (int m = KW - 1; m >= 0; --m) {
                s = vop<IS_MIN>(s, v[m]);
                Sprev[m] = s;
            }
        }
    }
}

template<bool INTERIOR>
__device__ __forceinline__ void tile_body(const float* __restrict__ src,
                                          float* __restrict__ dst,
                                          int R, int C, float* B, int t) {
    // ---- P0: colmin, global -> B[85][SB] cols j in [0,108) ----
    // B row o = img row R-11+o; window = img rows [R-22+o, R-1+o].
    if (t < 216) {
        const int ch = t >= 108;
        const int j = t - ch * 108;
        const int base_o = ch ? 43 : 0;
        const int cout = ch ? 42 : 43;
        int cj = C - 22 + j;
        bool colOK = true;
        if (!INTERIOR) {
            colOK = (unsigned)cj < WW;
            cj = cj < 0 ? 0 : (cj > WW - 1 ? WW - 1 : cj);
        }
        const float* col = src + cj;
        const int rbase = R - 22 + base_o;
        vanherk<true, 43>(cout,
            [&](int p) {
                int r = rbase + p;
                if (INTERIOR) return col[r * WW];
                int rc = r < 0 ? 0 : (r > HH - 1 ? HH - 1 : r);
                float v = col[rc * WW];
                return (colOK && (unsigned)r < HH) ? v : PINF;
            },
            [&](int k, float v) { B[(base_o + k) * SB + j] = v; });
    }
    __syncthreads();

    // ---- P1: rowmin -> eroded(o, e), e in [0,85), in-place ----
    // eroded e = img col C-11+e; window = B cols [e, e+21].
    {
        float res[44];
        const bool act = t < 170;
        int o = 0, e0 = 0;
        if (act) {
            o = t >> 1;
            const int ch = t & 1;
            e0 = ch ? 44 : 0;
            const int cout = ch ? 41 : 44;
            const int n = cout + KW - 1;              // 65 / 62 inputs
            float in[68];
            const float4* Br = (const float4*)(B + o * SB + e0);
            #pragma unroll
            for (int i = 0; i < 17; ++i) {
                if (4 * i < n) {
                    float4 x = Br[i];
                    in[4 * i] = x.x; in[4 * i + 1] = x.y;
                    in[4 * i + 2] = x.z; in[4 * i + 3] = x.w;
                }
            }
            vanherk<true, 44>(cout,
                [&](int p) { return in[p]; },
                [&](int k, float v) { res[k] = v; });
            if (!INTERIOR) {
                const bool rOK = (unsigned)(R - 11 + o) < HH;
                #pragma unroll
                for (int k = 0; k < 44; ++k) {
                    const int cimg = C - 11 + e0 + k;
                    if (!rOK || (unsigned)cimg >= WW) res[k] = -PINF;
                }
            }
        }
        __syncthreads();
        if (act) {
            float4* Bw = (float4*)(B + o * SB + e0);
            #pragma unroll
            for (int i = 0; i < 11; ++i)   // cols >=85 get garbage; never read
                Bw[i] = make_float4(res[4 * i], res[4 * i + 1],
                                    res[4 * i + 2], res[4 * i + 3]);
        }
        __syncthreads();
    }

    // ---- P2: rowmax(o, c), c in [0,64): window = eroded cols [c, c+21] ----
    {
        float res[32];
        const bool act = t < 170;
        int o = 0, c0 = 0;
        if (act) {
            o = t >> 1;
            c0 = (t & 1) * 32;
            float in[56];                              // cols [c0, c0+52] used
            const float4* Br = (const float4*)(B + o * SB + c0);
            #pragma unroll
            for (int i = 0; i < 14; ++i) {
                float4 x = Br[i];
                in[4 * i] = x.x; in[4 * i + 1] = x.y;
                in[4 * i + 2] = x.z; in[4 * i + 3] = x.w;
            }
            vanherk<false, 32>(32,
                [&](int p) { return in[p]; },
                [&](int k, float v) { res[k] = v; });
        }
        __syncthreads();
        if (act) {
            float4* Bw = (float4*)(B + o * SB + c0);
            #pragma unroll
            for (int i = 0; i < 8; ++i)
                Bw[i] = make_float4(res[4 * i], res[4 * i + 1],
                                    res[4 * i + 2], res[4 * i + 3]);
        }
        __syncthreads();
    }

    // ---- P3: colmax -> out. 128 threads = 64 cols x 2 row-chunks of 32. ----
    // out row R+y: window = B rows [y, y+21]; chunk reads 53 rows for 32 outs
    // (1.65 LDS reads/output vs 2.3 with 4x16 chunking).
    if (t < 128) {
        const int c = t & 63;
        const int y0 = (t >> 6) << 5;                  // {0,32}
        float o32[32];
        vanherk<false, 32>(32,
            [&](int p) { return B[(y0 + p) * SB + c]; },
            [&](int k, float v) { o32[k] = v; });
        #pragma unroll
        for (int k = 0; k < 32; ++k)
            dst[(R + y0 + k) * WW + C + c] = o32[k];
    }
}

__global__ __launch_bounds__(256) void fused_open(const float* __restrict__ in,
                                                  float* __restrict__ out) {
    __shared__ float B[85 * SB];                       // 39,440 B -> 4 blk/CU
    const int t = threadIdx.x;
    const int b = blockIdx.x;
    const int plane = b >> 8;
    const int by = (b >> 4) & 15;
    const int bx = b & 15;
    const int R = by * 64, C = bx * 64;
    const float* src = in + (size_t)plane * (HH * WW);
    float* dst = out + (size_t)plane * (HH * WW);

    if (by >= 1 && by <= 14 && bx >= 1 && bx <= 14)
        tile_body<true>(src, dst, R, C, B, t);
    else
        tile_body<false>(src, dst, R, C, B, t);
}

extern "C" void kernel_launch(void* const* d_in, const int* in_sizes, int n_in,
                              void* d_out, int out_size, void* d_ws, size_t ws_size,
                              hipStream_t stream) {
    const float* in = (const float*)d_in[0];
    float* out = (float*)d_out;
    (void)d_ws; (void)ws_size;
    fused_open<<<24 * 16 * 16, 256, 0, stream>>>(in, out);
}

// Round 5
// 187.159 us; speedup vs baseline: 1.0052x; 1.0052x over previous
//
#include <hip/hip_runtime.h>

// Fused morphological opening (22x22 flat SE), 8x3x1024x1024 f32, one kernel.
// opening = dilate(erode(x)); separable. Per 64x64 output tile:
//   P0: colmin streamed global->regs->LDS (B: 86 rows x 116 stride)
//   P1: rowmin -> eroded (+ -inf border override)   } fused, same wave owns
//   P2: rowmax over eroded                          } row (lanes 2o,2o+1) --
//       no barriers, just __threadfence_block() compiler fences
//   P3: colmax -> coalesced global store (threads 128..255)
// ALL van Herk instances have compile-time COUT -> zero runtime predication.
// Uniform chunk sizes (garbage outputs land in padding, never read).
// Window for index i: [i-11, i+10]. Erosion pads +inf; eroded values outside
// the image are -inf for dilation (border override in P1).

#define HH 1024
#define WW 1024
#define KW 22
#define SB 116            // floats per B row; 29 f4-groups (odd -> banks spread)
#define PINF __builtin_inff()

template<bool IS_MIN>
__device__ __forceinline__ float vop(float a, float b) {
    return IS_MIN ? fminf(a, b) : fmaxf(a, b);
}

// van Herk / Gil-Werman, compile-time output count COUT (window KW=22).
// get(p): input at window-space p (output k's window = get(k..k+21)).
// All bounds fold at compile time after unrolling -> no cndmask guards.
template<bool IS_MIN, int COUT, class Get, class Put>
__device__ __forceinline__ void vanherk(Get get, Put put) {
    constexpr int NIN = COUT + KW - 1;
    constexpr int NB = (NIN + KW - 1) / KW;
    const float ID = IS_MIN ? PINF : -PINF;
    float Sprev[KW];
    #pragma unroll
    for (int j = 0; j < NB; ++j) {
        const int base = KW * j;
        const int needed = (NIN - base) < KW ? (NIN - base) : KW;
        float v[KW];
        #pragma unroll
        for (int m = 0; m < KW; ++m)
            if (m < needed) v[m] = get(base + m);
        float p = ID;
        #pragma unroll
        for (int m = 0; m < KW; ++m) {
            if (m < needed) {
                p = vop<IS_MIN>(p, v[m]);
                const int k = base - (KW - 1) + m;
                if (k >= 0 && k < COUT) {
                    if (m == KW - 1) put(k, p);
                    else             put(k, vop<IS_MIN>(Sprev[m + 1], p));
                }
            }
        }
        if (j < NB - 1) {
            float s = ID;
            #pragma unroll
            for (int m = KW - 1; m >= 0; --m) {
                s = vop<IS_MIN>(s, v[m]);
                Sprev[m] = s;
            }
        }
    }
}

template<bool INTERIOR>
__device__ __forceinline__ void tile_body(const float* __restrict__ src,
                                          float* __restrict__ dst,
                                          int R, int C, float* B, int t) {
    // ---- P0: colmin, global -> B rows [0,86) x cols j in [0,108). ----
    // B row o = img row R-11+o; window = img rows [R-22+o, R-1+o].
    // 216 threads = 108 cols x 2 uniform chunks of 43 rows (row 85 garbage).
    if (t < 216) {
        const int ch = t >= 108;
        const int j = ch ? t - 108 : t;
        const int base_o = ch ? 43 : 0;
        int cj = C - 22 + j;
        bool colOK = true;
        if (!INTERIOR) {
            colOK = (unsigned)cj < WW;
            cj = cj < 0 ? 0 : (cj > WW - 1 ? WW - 1 : cj);
        }
        const float* col = src + cj;
        const int rbase = R - 22 + base_o;
        vanherk<true, 43>(
            [&](int p) {
                int r = rbase + p;
                if (INTERIOR) return col[r * WW];
                int rc = r < 0 ? 0 : (r > HH - 1 ? HH - 1 : r);
                float vv = col[rc * WW];
                return (colOK && (unsigned)r < HH) ? vv : PINF;
            },
            [&](int k, float vv) { B[(base_o + k) * SB + j] = vv; });
    }
    __syncthreads();

    // ---- P1+P2 fused: row o owned by lanes 2o, 2o+1 (same wave). ----
    // No barriers inside: in-wave lockstep orders cross-lane LDS hazards;
    // __threadfence_block() stops the COMPILER from reordering phases.
    if (t < 170) {
        const int o = t >> 1;
        const int half = t & 1;
        float* Brow = B + o * SB;

        // P1: rowmin. eroded e = img col C-11+e; window = B cols [e, e+21].
        // 2 uniform chunks of 44 (cols 85..87 garbage, within stride).
        const int e0 = half * 44;
        float in1[68];
        {
            const float4* Br = (const float4*)(Brow + e0);
            #pragma unroll
            for (int i = 0; i < 17; ++i) {            // cols [e0, e0+68)
                float4 x = Br[i];
                in1[4 * i] = x.x; in1[4 * i + 1] = x.y;
                in1[4 * i + 2] = x.z; in1[4 * i + 3] = x.w;
            }
        }
        float er[44];
        vanherk<true, 44>(
            [&](int p) { return in1[p]; },
            [&](int k, float vv) { er[k] = vv; });
        if (!INTERIOR) {
            const bool rOK = (unsigned)(R - 11 + o) < HH;
            #pragma unroll
            for (int k = 0; k < 44; ++k) {
                const int cimg = C - 11 + e0 + k;
                if (!rOK || (unsigned)cimg >= WW) er[k] = -PINF;
            }
        }
        __threadfence_block();                        // reads before writes
        {
            float4* Bw = (float4*)(Brow + e0);
            #pragma unroll
            for (int i = 0; i < 11; ++i)
                Bw[i] = make_float4(er[4 * i], er[4 * i + 1],
                                    er[4 * i + 2], er[4 * i + 3]);
        }
        __threadfence_block();                        // P1 writes before P2 reads

        // P2: rowmax(o, c) = max over eroded cols [c, c+21]; 2 chunks of 32.
        const int c0 = half * 32;
        float in2[56];
        {
            const float4* Br = (const float4*)(Brow + c0);
            #pragma unroll
            for (int i = 0; i < 14; ++i) {            // cols [c0, c0+56)
                float4 x = Br[i];
                in2[4 * i] = x.x; in2[4 * i + 1] = x.y;
                in2[4 * i + 2] = x.z; in2[4 * i + 3] = x.w;
            }
        }
        float rx[32];
        vanherk<false, 32>(
            [&](int p) { return in2[p]; },
            [&](int k, float vv) { rx[k] = vv; });
        __threadfence_block();                        // reads before writes
        {
            float4* Bw = (float4*)(Brow + c0);
            #pragma unroll
            for (int i = 0; i < 8; ++i)
                Bw[i] = make_float4(rx[4 * i], rx[4 * i + 1],
                                    rx[4 * i + 2], rx[4 * i + 3]);
        }
    }
    __syncthreads();

    // ---- P3: colmax -> out, threads 128..255 (waves 2,3). ----
    // out row R+y: window = B rows [y, y+21]; 64 cols x 2 chunks of 32 rows.
    if (t >= 128) {
        const int tt = t - 128;
        const int c = tt & 63;
        const int y0 = (tt >> 6) << 5;                // {0,32}
        float o32[32];
        vanherk<false, 32>(
            [&](int p) { return B[(y0 + p) * SB + c]; },
            [&](int k, float vv) { o32[k] = vv; });
        #pragma unroll
        for (int k = 0; k < 32; ++k)
            dst[(R + y0 + k) * WW + C + c] = o32[k];
    }
}

__global__ __launch_bounds__(256, 4) void fused_open(const float* __restrict__ in,
                                                     float* __restrict__ out) {
    __shared__ float B[86 * SB];                      // 39,904 B -> 4 blk/CU
    const int t = threadIdx.x;
    const int b = blockIdx.x;
    const int plane = b >> 8;
    const int by = (b >> 4) & 15;
    const int bx = b & 15;
    const int R = by * 64, C = bx * 64;
    const float* src = in + (size_t)plane * (HH * WW);
    float* dst = out + (size_t)plane * (HH * WW);

    if (by >= 1 && by <= 14 && bx >= 1 && bx <= 14)
        tile_body<true>(src, dst, R, C, B, t);
    else
        tile_body<false>(src, dst, R, C, B, t);
}

extern "C" void kernel_launch(void* const* d_in, const int* in_sizes, int n_in,
                              void* d_out, int out_size, void* d_ws, size_t ws_size,
                              hipStream_t stream) {
    const float* in = (const float*)d_in[0];
    float* out = (float*)d_out;
    (void)d_ws; (void)ws_size;
    fused_open<<<24 * 16 * 16, 256, 0, stream>>>(in, out);
}

// Round 6
// 184.386 us; speedup vs baseline: 1.0203x; 1.0150x over previous
//
#include <hip/hip_runtime.h>

// Fused morphological opening (22x22 flat SE), 8x3x1024x1024 f32, one kernel.
// opening = dilate(erode(x)); separable. Per 64x64 output tile:
//   P0: colmin streamed global->regs->LDS   (B: 86 rows x stride 116)
//   P1: rowmin -> eroded (+ -inf border override), in-place, f4 I/O
//   P2: rowmax over eroded, in-place, f4 I/O
//   P3: colmax -> coalesced global store
// EVERY phase is balanced per WAVE INDEX (waves of a block map one-per-SIMD;
// thread-range gating starves whole SIMDs across all resident blocks):
//   P0: 54 lanes active in each of the 4 waves (consecutive cols -> coalesced)
//   P1: 255 thr = 85 rows x 3 uniform overlapping chunks (COUT=32, e0=28ch);
//       overlap regions recompute identical values -> benign duplicate writes
//   P2: 255 thr = 85 rows x 3 chunks (COUT=24, c0=20ch)
//   P3: 256 thr = 64 cols x 4 chunks of 16 rows
// Read-phase | barrier | write-phase ordering handles in-place hazards.
// B stride 116: f4 row ops start-bank phase 29*o mod 8 (odd) -> uniform;
// scalar col ops (lanes=cols) 2-way aliased (free).
// Window for index i: [i-11, i+10]. Erosion pads +inf; eroded values outside
// the image are -inf for dilation (border override in P1).

#define HH 1024
#define WW 1024
#define KW 22
#define SB 116
#define PINF __builtin_inff()

template<bool IS_MIN>
__device__ __forceinline__ float vop(float a, float b) {
    return IS_MIN ? fminf(a, b) : fmaxf(a, b);
}

// van Herk / Gil-Werman, compile-time output count COUT (window KW=22).
// get(p): input at window-space p (output k's window = get(k..k+21)).
template<bool IS_MIN, int COUT, class Get, class Put>
__device__ __forceinline__ void vanherk(Get get, Put put) {
    constexpr int NIN = COUT + KW - 1;
    constexpr int NB = (NIN + KW - 1) / KW;
    const float ID = IS_MIN ? PINF : -PINF;
    float Sprev[KW];
    #pragma unroll
    for (int j = 0; j < NB; ++j) {
        const int base = KW * j;
        const int needed = (NIN - base) < KW ? (NIN - base) : KW;
        float v[KW];
        #pragma unroll
        for (int m = 0; m < KW; ++m)
            if (m < needed) v[m] = get(base + m);
        float p = ID;
        #pragma unroll
        for (int m = 0; m < KW; ++m) {
            if (m < needed) {
                p = vop<IS_MIN>(p, v[m]);
                const int k = base - (KW - 1) + m;
                if (k >= 0 && k < COUT) {
                    if (m == KW - 1) put(k, p);
                    else             put(k, vop<IS_MIN>(Sprev[m + 1], p));
                }
            }
        }
        if (j < NB - 1) {
            float s = ID;
            #pragma unroll
            for (int m = KW - 1; m >= 0; --m) {
                s = vop<IS_MIN>(s, v[m]);
                Sprev[m] = s;
            }
        }
    }
}

template<bool INTERIOR>
__device__ __forceinline__ void tile_body(const float* __restrict__ src,
                                          float* __restrict__ dst,
                                          int R, int C, float* B, int t) {
    const int w = t >> 6, slot = t & 63;

    // ---- P0: colmin, global -> B rows [0,86) x cols j in [0,108). ----
    // B row o = img row R-11+o; window = img rows [R-22+o, R-1+o].
    // wave = 2*rowchunk + colhalf; lanes 0..53 = consecutive cols.
    if (slot < 54) {
        const int ch = w >> 1;
        const int j = (w & 1) * 54 + slot;
        const int base_o = ch * 43;
        int cj = C - 22 + j;
        bool colOK = true;
        if (!INTERIOR) {
            colOK = (unsigned)cj < WW;
            cj = cj < 0 ? 0 : (cj > WW - 1 ? WW - 1 : cj);
        }
        const float* col = src + cj;
        const int rbase = R - 22 + base_o;
        vanherk<true, 43>(
            [&](int p) {
                int r = rbase + p;
                if (INTERIOR) return col[r * WW];
                int rc = r < 0 ? 0 : (r > HH - 1 ? HH - 1 : r);
                float vv = col[rc * WW];
                return (colOK && (unsigned)r < HH) ? vv : PINF;
            },
            [&](int k, float vv) { B[(base_o + k) * SB + j] = vv; });
    }
    __syncthreads();

    // ---- P1: rowmin -> eroded(o, e). 85 rows x 3 chunks, COUT=32. ----
    // eroded e = img col C-11+e; window = B cols [e, e+21].
    // chunk ch: e0 = 28ch (outputs overlap; duplicates identical).
    {
        const bool act = t < 255;
        const int ch = (3 * t + 2) >> 8;          // t/85 for t<255
        const int o = t - 85 * ch;
        const int g0 = 7 * ch;                    // e0 = 28ch = 4*g0
        float* Brow = B + o * SB;
        float in1[56];
        if (act) {
            #pragma unroll
            for (int i = 0; i < 14; ++i) {        // B cols [28ch, 28ch+56)
                float4 x = ((const float4*)Brow)[g0 + i];
                in1[4 * i] = x.x; in1[4 * i + 1] = x.y;
                in1[4 * i + 2] = x.z; in1[4 * i + 3] = x.w;
            }
        }
        float er[32];
        if (act) {
            vanherk<true, 32>(
                [&](int p) { return in1[p]; },
                [&](int k, float vv) { er[k] = vv; });
            if (!INTERIOR) {
                const bool rOK = (unsigned)(R - 11 + o) < HH;
                #pragma unroll
                for (int k = 0; k < 32; ++k) {
                    const int cimg = C - 11 + 28 * ch + k;
                    if (!rOK || (unsigned)cimg >= WW) er[k] = -PINF;
                }
            }
        }
        __syncthreads();                          // all reads before any write
        if (act) {
            #pragma unroll
            for (int i = 0; i < 8; ++i)           // er cols [28ch, 28ch+32)
                ((float4*)Brow)[g0 + i] =
                    make_float4(er[4 * i], er[4 * i + 1],
                                er[4 * i + 2], er[4 * i + 3]);
        }
        __syncthreads();
    }

    // ---- P2: rowmax(o, c) = max over eroded cols [c, c+21]. ----
    // 85 rows x 3 chunks, COUT=24, c0 = 20ch.
    {
        const bool act = t < 255;
        const int ch = (3 * t + 2) >> 8;
        const int o = t - 85 * ch;
        const int g0 = 5 * ch;                    // c0 = 20ch = 4*g0
        float* Brow = B + o * SB;
        float in2[48];
        if (act) {
            #pragma unroll
            for (int i = 0; i < 12; ++i) {        // er cols [20ch, 20ch+48)
                float4 x = ((const float4*)Brow)[g0 + i];
                in2[4 * i] = x.x; in2[4 * i + 1] = x.y;
                in2[4 * i + 2] = x.z; in2[4 * i + 3] = x.w;
            }
        }
        float rx[24];
        if (act) {
            vanherk<false, 24>(
                [&](int p) { return in2[p]; },
                [&](int k, float vv) { rx[k] = vv; });
        }
        __syncthreads();                          // all reads before any write
        if (act) {
            #pragma unroll
            for (int i = 0; i < 6; ++i)           // cols [20ch, 20ch+24)
                ((float4*)Brow)[g0 + i] =
                    make_float4(rx[4 * i], rx[4 * i + 1],
                                rx[4 * i + 2], rx[4 * i + 3]);
        }
        __syncthreads();
    }

    // ---- P3: colmax -> out. 64 cols x 4 chunks of 16 rows (all waves). ----
    // out row R+y: window = B rows [y, y+21].
    {
        const int c = t & 63;
        const int y0 = (t >> 6) << 4;             // {0,16,32,48}
        float o16[16];
        vanherk<false, 16>(
            [&](int p) { return B[(y0 + p) * SB + c]; },
            [&](int k, float vv) { o16[k] = vv; });
        #pragma unroll
        for (int k = 0; k < 16; ++k)
            dst[(R + y0 + k) * WW + C + c] = o16[k];
    }
}

__global__ __launch_bounds__(256, 4) void fused_open(const float* __restrict__ in,
                                                     float* __restrict__ out) {
    __shared__ float B[86 * SB];                  // 39,904 B -> 4 blk/CU
    const int t = threadIdx.x;
    const int b = blockIdx.x;
    const int plane = b >> 8;
    const int by = (b >> 4) & 15;
    const int bx = b & 15;
    const int R = by * 64, C = bx * 64;
    const float* src = in + (size_t)plane * (HH * WW);
    float* dst = out + (size_t)plane * (HH * WW);

    if (by >= 1 && by <= 14 && bx >= 1 && bx <= 14)
        tile_body<true>(src, dst, R, C, B, t);
    else
        tile_body<false>(src, dst, R, C, B, t);
}

extern "C" void kernel_launch(void* const* d_in, const int* in_sizes, int n_in,
                              void* d_out, int out_size, void* d_ws, size_t ws_size,
                              hipStream_t stream) {
    const float* in = (const float*)d_in[0];
    float* out = (float*)d_out;
    (void)d_ws; (void)ws_size;
    fused_open<<<24 * 16 * 16, 256, 0, stream>>>(in, out);
}